// Round 1
// baseline (1297.879 us; speedup 1.0000x reference)
//
#include <hip/hip_runtime.h>
#include <math.h>

// LabelSmoothingLoss: pred (N x V fp32), target (N int), scalar out.
// Closed-form per row (tgt != 0):
//   eps = 0.1/(V-2); conf = 0.9
//   tlogt = 0.1*log(eps) + conf*log(conf)                      (constant)
//   tlogp = eps*(Srow - lp0 - lpt) + conf*lpt
//     where Srow = sum_j pred[row,j] - V*logZ, lp0/lpt = pred@{0,tgt} - logZ
//   row_loss = tlogt - tlogp ; out = sum(row_loss)/N
// Single pass over pred: online softmax (m, s), plain sum, capture 2 elements.

__global__ void zero_out_kernel(float* out) { out[0] = 0.0f; }

__global__ __launch_bounds__(256) void label_smooth_loss_kernel(
    const float* __restrict__ pred,
    const int* __restrict__ target,
    float* __restrict__ out,
    int n_tokens, int vocab)
{
    const int row = blockIdx.x;
    const int tid = threadIdx.x;
    const int tgt = target[row];

    const float4* rowp = (const float4*)(pred + (size_t)row * (size_t)vocab);
    const int nvec = vocab >> 2;  // 32000/4 = 8000, float4-aligned rows

    float m   = -INFINITY;  // running max
    float s   = 0.0f;       // running sum of exp(x - m)
    float tot = 0.0f;       // plain sum of x

    __shared__ float sh_p0, sh_pt;
    __shared__ float red_m[4], red_s[4], red_t[4];

    for (int j = tid; j < nvec; j += 256) {
        float4 v = rowp[j];
        const int base = j << 2;
        float xs[4] = {v.x, v.y, v.z, v.w};
        #pragma unroll
        for (int c = 0; c < 4; ++c) {
            float x = xs[c];
            tot += x;
            // branch-free online softmax update
            float mn = fmaxf(m, x);
            s = s * __expf(m - mn) + __expf(x - mn);
            m = mn;
            int col = base + c;
            if (col == tgt) sh_pt = x;   // unique finder, no race
            if (col == 0)   sh_p0 = x;   // thread 0, j==0, c==0
        }
    }

    // wave64 shuffle reduction of (m, s) and tot
    #pragma unroll
    for (int off = 32; off >= 1; off >>= 1) {
        float m2 = __shfl_down(m, off);
        float s2 = __shfl_down(s, off);
        float t2 = __shfl_down(tot, off);
        float mn = fmaxf(m, m2);
        s = s * __expf(m - mn) + s2 * __expf(m2 - mn);
        m = mn;
        tot += t2;
    }
    const int wave = tid >> 6;
    if ((tid & 63) == 0) { red_m[wave] = m; red_s[wave] = s; red_t[wave] = tot; }
    __syncthreads();

    if (tid == 0) {
        m = red_m[0]; s = red_s[0]; tot = red_t[0];
        #pragma unroll
        for (int w = 1; w < 4; ++w) {
            float m2 = red_m[w], s2 = red_s[w];
            float mn = fmaxf(m, m2);
            s = s * __expf(m - mn) + s2 * __expf(m2 - mn);
            m = mn;
            tot += red_t[w];
        }
        if (tgt != 0) {
            const float conf = 0.9f;
            const float eps  = 0.1f / (float)(vocab - 2);
            float logZ = m + logf(s);
            float lp0  = sh_p0 - logZ;
            float lpt  = sh_pt - logZ;
            float S    = tot - (float)vocab * logZ;   // sum of logp over row
            float tlogp = eps * (S - lp0 - lpt) + conf * lpt;
            float tlogt = 0.1f * logf(eps) + conf * logf(conf);
            atomicAdd(out, (tlogt - tlogp) / (float)n_tokens);
        }
    }
}

extern "C" void kernel_launch(void* const* d_in, const int* in_sizes, int n_in,
                              void* d_out, int out_size, void* d_ws, size_t ws_size,
                              hipStream_t stream) {
    const float* pred  = (const float*)d_in[0];
    const int*   target = (const int*)d_in[1];
    float* out = (float*)d_out;

    const int n_tokens = in_sizes[1];
    const int vocab    = in_sizes[0] / n_tokens;

    zero_out_kernel<<<1, 1, 0, stream>>>(out);
    label_smooth_loss_kernel<<<n_tokens, 256, 0, stream>>>(pred, target, out,
                                                           n_tokens, vocab);
}